// Round 1
// baseline (205.199 us; speedup 1.0000x reference)
//
#include <hip/hip_runtime.h>
#include <climits>

#define A_TOT 8400
#define NCLS  80
#define MGT   64
#define TK    13
#define EPS7  1e-7f
#define EPS9  1e-9f
#define INV_PI2 0.4052847345693511f   // 4/pi^2

__device__ __forceinline__ bool better_pair(float v1, int i1, float v2, int i2) {
  // lax.top_k order: value descending, index ascending on ties
  return (v1 > v2) || (v1 == v2 && i1 < i2);
}

__device__ __forceinline__ float ciou_clip(
    float gx1, float gy1, float gx2, float gy2, float ga, float area1,
    float px1, float py1, float px2, float py2, float pa)
{
  float w2 = px2 - px1, h2 = py2 - py1 + EPS7;
  float iw = fmaxf(fminf(gx2, px2) - fmaxf(gx1, px1), 0.f);
  float ih = fmaxf(fminf(gy2, py2) - fmaxf(gy1, py1), 0.f);
  float inter = iw * ih;
  float uni = area1 + w2 * h2 - inter + EPS7;
  float iou = inter / uni;
  float cw = fmaxf(gx2, px2) - fminf(gx1, px1);
  float ch = fmaxf(gy2, py2) - fminf(gy1, py1);
  float c2 = cw * cw + ch * ch + EPS7;
  float dx = px1 + px2 - gx1 - gx2;
  float dy = py1 + py2 - gy1 - gy2;
  float rho2 = (dx * dx + dy * dy) * 0.25f;
  float dd = pa - ga;
  float v = INV_PI2 * dd * dd;
  float alpha = v / (v - iou + (1.f + EPS7));
  float c = iou - (rho2 / c2 + v * alpha);
  return fmaxf(c, 0.f);   // overlaps = ciou.clip(0)
}

// Precompute atan(w/h) per pred box and per gt box.
__global__ void k_pre(const float* __restrict__ pd_bboxes,
                      const float* __restrict__ gt_bboxes,
                      float* __restrict__ patan, float* __restrict__ gatan, int bs)
{
  int t = blockIdx.x * 256 + threadIdx.x;
  int np = bs * A_TOT;
  if (t < np) {
    float4 bx = ((const float4*)pd_bboxes)[t];
    patan[t] = atanf((bx.z - bx.x) / (bx.w - bx.y + EPS7));
  } else if (t < np + bs * MGT) {
    int r = t - np;
    float4 bx = ((const float4*)gt_bboxes)[r];
    gatan[r] = atanf((bx.z - bx.x) / (bx.w - bx.y + EPS7));
  }
}

// One block per (b,m) row: compute metric = score * ciou^6 * in_gts over A,
// exact top-13 with lax.top_k tie semantics. Writes idx (or -1 if not a
// positive: !in_gts or invalid gt) for each of the 13 slots.
__global__ __launch_bounds__(256)
void k_topk(const float* __restrict__ pd_scores,
            const float* __restrict__ pd_bboxes,
            const float* __restrict__ anc,
            const int* __restrict__ gt_labels,
            const float* __restrict__ gt_bboxes,
            const float* __restrict__ mask_gt,
            const float* __restrict__ patan,
            const float* __restrict__ gatan,
            int* __restrict__ topk_out)
{
  int row = blockIdx.x;                 // b*MGT + m
  int b = row / MGT;
  if (mask_gt[row] <= 0.f) {            // invalid gt: contributes nothing
    if (threadIdx.x < TK) topk_out[row * TK + threadIdx.x] = -1;
    return;
  }
  float4 g = ((const float4*)gt_bboxes)[row];
  float ga = gatan[row];
  float area1 = (g.z - g.x) * (g.w - g.y + EPS7);
  int label = gt_labels[row];
  const float*  ps   = pd_scores + (size_t)b * A_TOT * NCLS + label;
  const float4* pb   = (const float4*)(pd_bboxes + (size_t)b * A_TOT * 4);
  const float*  pat  = patan + (size_t)b * A_TOT;
  const float2* anc2 = (const float2*)anc;

  // thread-local top-13 (sorted desc by (val, -idx))
  float lv[TK]; int li[TK];
#pragma unroll
  for (int k = 0; k < TK; ++k) { lv[k] = -1.f; li[k] = INT_MAX; }

  for (int a = threadIdx.x; a < A_TOT; a += 256) {
    float4 p = pb[a];
    float2 an = anc2[a];
    float dmin = fminf(fminf(an.x - g.x, an.y - g.y), fminf(g.z - an.x, g.w - an.y));
    float metric = 0.f;
    if (dmin > EPS9) {
      float ov = ciou_clip(g.x, g.y, g.z, g.w, ga, area1, p.x, p.y, p.z, p.w, pat[a]);
      float o2 = ov * ov;
      metric = ps[(size_t)a * NCLS] * (o2 * o2 * o2);
    }
    if (better_pair(metric, a, lv[TK - 1], li[TK - 1])) {
      int pos = TK - 1;
      while (pos > 0 && better_pair(metric, a, lv[pos - 1], li[pos - 1])) {
        lv[pos] = lv[pos - 1]; li[pos] = li[pos - 1]; --pos;
      }
      lv[pos] = metric; li[pos] = a;
    }
  }

  // block merge: 13 iterations of block-wide arg-best over per-thread heads
  __shared__ float sv[256];
  __shared__ int   si[256];
  __shared__ int   chosen[TK];
  int ptr = 0;
  for (int k = 0; k < TK; ++k) {
    float cv = (ptr < TK) ? lv[ptr] : -2.f;
    int   ci = (ptr < TK) ? li[ptr] : INT_MAX;
    sv[threadIdx.x] = cv; si[threadIdx.x] = ci;
    __syncthreads();
    for (int s = 128; s > 0; s >>= 1) {
      if (threadIdx.x < s) {
        float v2 = sv[threadIdx.x + s]; int i2 = si[threadIdx.x + s];
        if (better_pair(v2, i2, sv[threadIdx.x], si[threadIdx.x])) {
          sv[threadIdx.x] = v2; si[threadIdx.x] = i2;
        }
      }
      __syncthreads();
    }
    float bv = sv[0]; int bi = si[0];
    if (threadIdx.x == 0) chosen[k] = bi;
    __syncthreads();
    if (ptr < TK && cv == bv && ci == bi) ++ptr;   // unique winner advances
  }

  if (threadIdx.x < TK) {
    int idx = chosen[threadIdx.x];
    float2 an = anc2[idx];
    float dmin = fminf(fminf(an.x - g.x, an.y - g.y), fminf(g.z - an.x, g.w - an.y));
    topk_out[row * TK + threadIdx.x] = (dmin > EPS9) ? idx : -1;  // mask_topk*in_gts*mask_gt
  }
}

__global__ void k_scatter(const int* __restrict__ topk, int* __restrict__ fg_cnt,
                          int* __restrict__ m_sum, int n)
{
  int e = blockIdx.x * 256 + threadIdx.x;
  if (e >= n) return;
  int idx = topk[e];
  if (idx < 0) return;
  int row = e / TK;
  int b = row / MGT, m = row - b * MGT;
  int t = b * A_TOT + idx;
  atomicAdd(fg_cnt + t, 1);
  atomicAdd(m_sum + t, m);
}

// Per (b,a): resolve multi-assignment (argmax over m of overlaps, first-max),
// compute align_metric at the final assignment, build pos_align/pos_overlaps
// via float-bits atomicMax (all values >= 0).
__global__ __launch_bounds__(256)
void k_resolve(const float* __restrict__ pd_scores,
               const float* __restrict__ pd_bboxes,
               const int* __restrict__ gt_labels,
               const float* __restrict__ gt_bboxes,
               const float* __restrict__ patan,
               const float* __restrict__ gatan,
               const int* __restrict__ fg_cnt,
               const int* __restrict__ m_sum,
               int* __restrict__ tgt_ws, float* __restrict__ am_ws,
               unsigned int* __restrict__ pos_al, unsigned int* __restrict__ pos_ov,
               int bs)
{
  int t = blockIdx.x * 256 + threadIdx.x;
  if (t >= bs * A_TOT) return;
  int cnt = fg_cnt[t];
  if (cnt == 0) { tgt_ws[t] = 0; am_ws[t] = 0.f; return; }
  int b = t / A_TOT;
  float4 p = ((const float4*)pd_bboxes)[t];
  float pa = patan[t];
  int tgt; float ov;
  if (cnt == 1) {
    tgt = m_sum[t];
    float4 g = ((const float4*)gt_bboxes)[b * MGT + tgt];
    float area1 = (g.z - g.x) * (g.w - g.y + EPS7);
    ov = ciou_clip(g.x, g.y, g.z, g.w, gatan[b * MGT + tgt], area1,
                   p.x, p.y, p.z, p.w, pa);
  } else {
    tgt = 0; ov = -1.f;
    for (int m = 0; m < MGT; ++m) {     // argmax over ALL m, first-max wins
      float4 g = ((const float4*)gt_bboxes)[b * MGT + m];
      float area1 = (g.z - g.x) * (g.w - g.y + EPS7);
      float o = ciou_clip(g.x, g.y, g.z, g.w, gatan[b * MGT + m], area1,
                          p.x, p.y, p.z, p.w, pa);
      if (o > ov) { ov = o; tgt = m; }
    }
  }
  int label = gt_labels[b * MGT + tgt];
  float sc = pd_scores[(size_t)t * NCLS + label];
  float o2 = ov * ov;
  float am = sc * (o2 * o2 * o2);
  tgt_ws[t] = tgt; am_ws[t] = am;
  atomicMax(pos_al + b * MGT + tgt, __float_as_uint(am));
  atomicMax(pos_ov + b * MGT + tgt, __float_as_uint(ov));
}

// Final outputs. Score rows written cooperatively, fully-coalesced float4.
__global__ __launch_bounds__(256)
void k_write(const int* __restrict__ fg_cnt, const int* __restrict__ tgt_ws,
             const float* __restrict__ am_ws,
             const unsigned int* __restrict__ pos_al,
             const unsigned int* __restrict__ pos_ov,
             const int* __restrict__ gt_labels, const float* __restrict__ gt_bboxes,
             float* __restrict__ out, int bs)
{
  __shared__ int   slab[256];
  __shared__ float snorm[256];
  int total = bs * A_TOT;
  int base = blockIdx.x * 256;
  int t = base + threadIdx.x;
  int nrows = total - base; if (nrows > 256) nrows = 256;
  size_t OFF_BOX = (size_t)total;
  size_t OFF_SCR = OFF_BOX + (size_t)total * 4;
  size_t OFF_FG  = OFF_SCR + (size_t)total * NCLS;
  size_t OFF_TGT = OFF_FG + (size_t)total;
  if (t < total) {
    int b = t / A_TOT;
    int cnt = fg_cnt[t];
    int tgt = tgt_ws[t];
    int gi = b * MGT + tgt;
    int lab = gt_labels[gi]; if (lab < 0) lab = 0;
    float4 box = ((const float4*)gt_bboxes)[gi];
    float nrm = 0.f;
    if (cnt > 0) {
      float pa_ = __uint_as_float(pos_al[gi]);
      float po  = __uint_as_float(pos_ov[gi]);
      nrm = am_ws[t] * po / (pa_ + EPS9);
    }
    out[t] = (float)lab;
    ((float4*)(out + OFF_BOX))[t] = box;
    out[OFF_FG + t]  = (cnt > 0) ? 1.f : 0.f;
    out[OFF_TGT + t] = (float)tgt;
    slab[threadIdx.x]  = lab;
    snorm[threadIdx.x] = (cnt > 0) ? nrm : 0.f;
  }
  __syncthreads();
  float4* srow = (float4*)(out + OFF_SCR + (size_t)base * NCLS);
  int nvec = nrows * (NCLS / 4);
  for (int u = threadIdx.x; u < nvec; u += 256) {
    int i  = u / (NCLS / 4);
    int c0 = (u - i * (NCLS / 4)) * 4;
    int lb = slab[i]; float nv = snorm[i];
    float4 v;
    v.x = (lb == c0    ) ? nv : 0.f;
    v.y = (lb == c0 + 1) ? nv : 0.f;
    v.z = (lb == c0 + 2) ? nv : 0.f;
    v.w = (lb == c0 + 3) ? nv : 0.f;
    srow[u] = v;
  }
}

extern "C" void kernel_launch(void* const* d_in, const int* in_sizes, int n_in,
                              void* d_out, int out_size, void* d_ws, size_t ws_size,
                              hipStream_t stream)
{
  const float* pd_scores = (const float*)d_in[0];
  const float* pd_bboxes = (const float*)d_in[1];
  const float* anc       = (const float*)d_in[2];
  const int*   gt_labels = (const int*)d_in[3];
  const float* gt_bboxes = (const float*)d_in[4];
  const float* mask_gt   = (const float*)d_in[5];
  int bs = in_sizes[0] / (A_TOT * NCLS);
  int NA = bs * A_TOT, NM = bs * MGT;

  // workspace layout (all 4-byte elems)
  float* patan = (float*)d_ws;                 // NA
  float* gatan = patan + NA;                   // NM
  int*   topk  = (int*)(gatan + NM);           // NM*TK
  int*   fg_cnt = topk + NM * TK;              // NA   <- zeroed
  int*   m_sum  = fg_cnt + NA;                 // NA   <- zeroed
  unsigned int* pos_al = (unsigned int*)(m_sum + NA);   // NM  <- zeroed
  unsigned int* pos_ov = pos_al + NM;          // NM   <- zeroed
  int*   tgt_ws = (int*)(pos_ov + NM);         // NA
  float* am_ws  = (float*)(tgt_ws + NA);       // NA

  hipMemsetAsync(fg_cnt, 0, (size_t)(2 * NA + 2 * NM) * sizeof(int), stream);

  k_pre<<<(NA + NM + 255) / 256, 256, 0, stream>>>(pd_bboxes, gt_bboxes, patan, gatan, bs);
  k_topk<<<NM, 256, 0, stream>>>(pd_scores, pd_bboxes, anc, gt_labels, gt_bboxes,
                                 mask_gt, patan, gatan, topk);
  k_scatter<<<(NM * TK + 255) / 256, 256, 0, stream>>>(topk, fg_cnt, m_sum, NM * TK);
  k_resolve<<<(NA + 255) / 256, 256, 0, stream>>>(pd_scores, pd_bboxes, gt_labels,
                                                  gt_bboxes, patan, gatan, fg_cnt,
                                                  m_sum, tgt_ws, am_ws, pos_al, pos_ov, bs);
  k_write<<<(NA + 255) / 256, 256, 0, stream>>>(fg_cnt, tgt_ws, am_ws, pos_al, pos_ov,
                                                gt_labels, gt_bboxes, (float*)d_out, bs);
}